// Round 10
// baseline (338.313 us; speedup 1.0000x reference)
//
#include <hip/hip_runtime.h>

#define EPS 1e-6f

// Sizes (fixed): B=4, N=1024, DIM=384, H=12, d=32, BH=48
// ws layout (floats): q[48*1024*32] | k[...] | v[...] | out_pre[4096*384]

// ---------------- Kernel 1: qkv = x @ w_qkv, relu+eps on q,k, scatter to [BH][N][32] ----------------
__global__ __launch_bounds__(256) void qkv_gemm(const float* __restrict__ x,
                                                const float* __restrict__ w,
                                                float* __restrict__ qw,
                                                float* __restrict__ kw,
                                                float* __restrict__ vw) {
    __shared__ float As[32][68];   // transposed A tile: As[k][row]
    __shared__ float Bs[32][68];   // natural B tile:    Bs[k][col]
    const int t = threadIdx.x;
    const int m0 = blockIdx.y * 64;
    const int c0 = blockIdx.x * 64;
    const int tx = t & 15, ty = t >> 4;

    float acc[4][4];
#pragma unroll
    for (int i = 0; i < 4; i++)
#pragma unroll
        for (int j = 0; j < 4; j++) acc[i][j] = 0.f;

    for (int k0 = 0; k0 < 384; k0 += 32) {
        __syncthreads();
#pragma unroll
        for (int l = 0; l < 2; l++) {
            int idx = t * 2 + l;
            int r = idx >> 3, c4 = (idx & 7) * 4;
            float4 a = *(const float4*)(x + (size_t)(m0 + r) * 384 + k0 + c4);
            As[c4 + 0][r] = a.x;
            As[c4 + 1][r] = a.y;
            As[c4 + 2][r] = a.z;
            As[c4 + 3][r] = a.w;
        }
#pragma unroll
        for (int l = 0; l < 2; l++) {
            int idx = t * 2 + l;
            int kr = idx >> 4, cc = (idx & 15) * 4;
            *(float4*)&Bs[kr][cc] = *(const float4*)(w + (size_t)(k0 + kr) * 1152 + c0 + cc);
        }
        __syncthreads();
#pragma unroll
        for (int kk = 0; kk < 32; kk++) {
            float4 a = *(float4*)&As[kk][ty * 4];
            float4 bb = *(float4*)&Bs[kk][tx * 4];
            float av[4] = {a.x, a.y, a.z, a.w};
            float bv[4] = {bb.x, bb.y, bb.z, bb.w};
#pragma unroll
            for (int i = 0; i < 4; i++)
#pragma unroll
                for (int j = 0; j < 4; j++) acc[i][j] += av[i] * bv[j];
        }
    }
    const int sec = (c0 + tx * 4) / 384;           // 0=q, 1=k, 2=v (uniform per block)
    float* dst = (sec == 0) ? qw : (sec == 1) ? kw : vw;
    const int cc0 = c0 + tx * 4 - sec * 384;
    const int h = cc0 >> 5, dd = cc0 & 31;
#pragma unroll
    for (int i = 0; i < 4; i++) {
        int row = m0 + ty * 4 + i;
        int b = row >> 10, n = row & 1023;
        float4 o;
        if (sec < 2) {
            o.x = fmaxf(acc[i][0], 0.f) + EPS;
            o.y = fmaxf(acc[i][1], 0.f) + EPS;
            o.z = fmaxf(acc[i][2], 0.f) + EPS;
            o.w = fmaxf(acc[i][3], 0.f) + EPS;
        } else {
            o = make_float4(acc[i][0], acc[i][1], acc[i][2], acc[i][3]);
        }
        *(float4*)(dst + (size_t)((b * 12 + h) * 1024 + n) * 32 + dd) = o;
    }
}

// ---------------- Kernel 2: Toeplitz-masked linear attention, LDS-free hot loop ----------------
// q,k,v: [48][1024][32]; tw: [2047]; op: [4096][384]
// R6/R7/R8 showed the limiter is the per-CU LDS pipe (~200us invariant across
// occupancy/conflict changes). This version keeps K[m][:] and V[m][:] in SGPRs
// (scalar loads on the SMEM pipe - addresses are wave-uniform via readfirstlane),
// Q row + f64 accumulators in VGPRs, and uses LDS only for the Toeplitz window
// (1 conflict-free b32/m) and a one-time end reduction. No barriers in main loop.
// S fma chain (d ascending f32) bit-identical to R3..R8; num/den f64, order
// = within-wave m ascending (stride 4), then waves 0+1+2+3 (deterministic).
__global__ __launch_bounds__(256) void toep_attn(const float* __restrict__ q,
                                                 const float* __restrict__ k,
                                                 const float* __restrict__ v,
                                                 const float* __restrict__ tw,
                                                 float* __restrict__ op) {
    const int t = threadIdx.x;
    const int r = t & 63;                                   // output row within tile
    const int wv = __builtin_amdgcn_readfirstlane(t >> 6);  // wave id, SGPR-uniform
    const int n0 = blockIdx.x * 64;
    const int bh = blockIdx.y;
    const int b = bh / 12, h = bh % 12;

    __shared__ float Tw[1088];       // tw[n0 .. n0+1086]
    __shared__ double red[64][33];   // end reduction: 32 num + den per row

    const float* qb = q + (size_t)bh * 32768;
    const float* kb = k + (size_t)bh * 32768;
    const float* vb = v + (size_t)bh * 32768;

    // stage Toeplitz window once: j in [0,1087), tw index n0+j <= 960+1086 = 2046 ok
    for (int j = t; j < 1087; j += 256) Tw[j] = tw[n0 + j];

    // Q row r -> 32 VGPRs (coalesced, once per block)
    float qr[32];
#pragma unroll
    for (int c = 0; c < 8; c++) {
        float4 f = *(const float4*)(qb + (size_t)(n0 + r) * 32 + c * 4);
        qr[c * 4 + 0] = f.x; qr[c * 4 + 1] = f.y;
        qr[c * 4 + 2] = f.z; qr[c * 4 + 3] = f.w;
    }
    __syncthreads();

    double num[32];
#pragma unroll
    for (int c = 0; c < 32; c++) num[c] = 0.0;
    double den = 0.0;

    // main loop: wave wv handles m = wv, wv+4, ... (256 iterations, no barriers)
    for (int m = wv; m < 1024; m += 4) {
        const float* kr = kb + (size_t)m * 32;   // wave-uniform -> scalar loads
        const float* vr = vb + (size_t)m * 32;   // wave-uniform -> scalar loads
        // f32 dot, d ascending: bit-identical chain to prior rounds
        float s = 0.f;
#pragma unroll
        for (int d = 0; d < 32; d++) s += qr[d] * kr[d];
        // Toeplitz mask: index (n0+r)-m+1023 - n0 = r-m+1023 in [0,1087)
        s *= Tw[r - m + 1023];
        double sd = (double)s;
        den += sd;
#pragma unroll
        for (int c = 0; c < 32; c++) num[c] += sd * (double)vr[c];
    }

    // cross-wave reduction (deterministic order w0+w1+w2+w3)
    if (wv == 0) {
#pragma unroll
        for (int c = 0; c < 32; c++) red[r][c] = num[c];
        red[r][32] = den;
    }
    __syncthreads();
    if (wv == 1) {
#pragma unroll
        for (int c = 0; c < 32; c++) red[r][c] += num[c];
        red[r][32] += den;
    }
    __syncthreads();
    if (wv == 2) {
#pragma unroll
        for (int c = 0; c < 32; c++) red[r][c] += num[c];
        red[r][32] += den;
    }
    __syncthreads();
    if (wv == 3) {
#pragma unroll
        for (int c = 0; c < 32; c++) red[r][c] += num[c];
        red[r][32] += den;
    }
    __syncthreads();

    // output: thread (r, colgroup wv) writes 8 cols of row n0+r
    {
        double inv = 1.0 / (red[r][32] + (double)EPS);
        float* o = op + (size_t)(b * 1024 + n0 + r) * 384 + h * 32 + wv * 8;
        float4 o0, o1;
        o0.x = (float)(red[r][wv * 8 + 0] * inv);
        o0.y = (float)(red[r][wv * 8 + 1] * inv);
        o0.z = (float)(red[r][wv * 8 + 2] * inv);
        o0.w = (float)(red[r][wv * 8 + 3] * inv);
        o1.x = (float)(red[r][wv * 8 + 4] * inv);
        o1.y = (float)(red[r][wv * 8 + 5] * inv);
        o1.z = (float)(red[r][wv * 8 + 6] * inv);
        o1.w = (float)(red[r][wv * 8 + 7] * inv);
        *(float4*)o = o0;
        *(float4*)(o + 4) = o1;
    }
}

// ---------------- Kernel 3: out = op @ w_out^T + b_out ----------------
__global__ __launch_bounds__(256) void out_gemm(const float* __restrict__ a,
                                                const float* __restrict__ w,
                                                const float* __restrict__ bias,
                                                float* __restrict__ out) {
    __shared__ float As[32][68];   // As[k][row]
    __shared__ float Bs[32][68];   // Bs[k][cout] = w[cout][k] transposed
    const int t = threadIdx.x;
    const int m0 = blockIdx.y * 64;
    const int c0 = blockIdx.x * 64;
    const int tx = t & 15, ty = t >> 4;

    float acc[4][4];
#pragma unroll
    for (int i = 0; i < 4; i++)
#pragma unroll
        for (int j = 0; j < 4; j++) acc[i][j] = 0.f;

    for (int k0 = 0; k0 < 384; k0 += 32) {
        __syncthreads();
#pragma unroll
        for (int l = 0; l < 2; l++) {
            int idx = t * 2 + l;
            int r = idx >> 3, c4 = (idx & 7) * 4;
            float4 av = *(const float4*)(a + (size_t)(m0 + r) * 384 + k0 + c4);
            As[c4 + 0][r] = av.x;
            As[c4 + 1][r] = av.y;
            As[c4 + 2][r] = av.z;
            As[c4 + 3][r] = av.w;
        }
#pragma unroll
        for (int l = 0; l < 2; l++) {
            int idx = t * 2 + l;
            int r = idx >> 3, c4 = (idx & 7) * 4;
            float4 wv = *(const float4*)(w + (size_t)(c0 + r) * 384 + k0 + c4);
            Bs[c4 + 0][r] = wv.x;
            Bs[c4 + 1][r] = wv.y;
            Bs[c4 + 2][r] = wv.z;
            Bs[c4 + 3][r] = wv.w;
        }
        __syncthreads();
#pragma unroll
        for (int kk = 0; kk < 32; kk++) {
            float4 a4 = *(float4*)&As[kk][ty * 4];
            float4 b4 = *(float4*)&Bs[kk][tx * 4];
            float av[4] = {a4.x, a4.y, a4.z, a4.w};
            float bv[4] = {b4.x, b4.y, b4.z, b4.w};
#pragma unroll
            for (int i = 0; i < 4; i++)
#pragma unroll
                for (int j = 0; j < 4; j++) acc[i][j] += av[i] * bv[j];
        }
    }
    const int col = c0 + tx * 4;
    float4 bb = *(const float4*)(bias + col);
#pragma unroll
    for (int i = 0; i < 4; i++) {
        int row = m0 + ty * 4 + i;
        float4 o = {acc[i][0] + bb.x, acc[i][1] + bb.y,
                    acc[i][2] + bb.z, acc[i][3] + bb.w};
        *(float4*)(out + (size_t)row * 384 + col) = o;
    }
}

extern "C" void kernel_launch(void* const* d_in, const int* in_sizes, int n_in,
                              void* d_out, int out_size, void* d_ws, size_t ws_size,
                              hipStream_t stream) {
    const float* x     = (const float*)d_in[0];
    const float* w_qkv = (const float*)d_in[1];
    const float* w_out = (const float*)d_in[2];
    const float* b_out = (const float*)d_in[3];
    const float* tw    = (const float*)d_in[4];
    float* out = (float*)d_out;

    float* qw = (float*)d_ws;            // 48*1024*32 = 1572864 floats
    float* kw = qw + 1572864;
    float* vw = kw + 1572864;
    float* op = vw + 1572864;            // 4096*384  = 1572864 floats

    qkv_gemm<<<dim3(18, 64), 256, 0, stream>>>(x, w_qkv, qw, kw, vw);
    toep_attn<<<dim3(16, 48), 256, 0, stream>>>(qw, kw, vw, tw, op);
    out_gemm<<<dim3(6, 64), 256, 0, stream>>>(op, w_out, b_out, out);
}